// Round 4
// baseline (100.596 us; speedup 1.0000x reference)
//
#include <hip/hip_runtime.h>
#include <stdint.h>

#define CI 512
#define CO 512
#define HI 64
#define WI 64
#define HY 65
#define NB 8

typedef __bf16 bf16x8 __attribute__((ext_vector_type(8)));
typedef float f32x4 __attribute__((ext_vector_type(4)));

__device__ __forceinline__ unsigned short f2bf(float f) {
  unsigned int u = __float_as_uint(f);
  return (unsigned short)((u + 0x7fffu + ((u >> 16) & 1u)) >> 16);
}

// async global->LDS, 16B per lane. LDS dest must be base + lane*16 (linear).
__device__ __forceinline__ void async16(void* lds, const void* g) {
  __builtin_amdgcn_global_load_lds(
      (const __attribute__((address_space(1))) uint32_t*)g,
      (__attribute__((address_space(3))) uint32_t*)lds, 16, 0, 0);
}

// ---------------- Kernel A: FIR prefilter (LDS-tiled separable) ----------------
#define CT 32
#define RT 13

__global__ __launch_bounds__(256) void fir_kernel(const float* __restrict__ x,
                                                  unsigned short* __restrict__ yt) {
  __shared__ float raw[CT][WI + 1];
  __shared__ float hrow[4][HY][CT];

  const int tid = threadIdx.x;
  const int bid = blockIdx.x;
  const int n = bid / 80;
  const int rem = bid % 80;
  const int c0 = (rem / 5) * CT;
  const int r0 = (rem % 5) * RT;

  const float* xb = x + ((size_t)n * CI + c0) * (HI * WI);

  const int lc = tid >> 3;
  const int lq = tid & 7;
  const int c = tid & (CT - 1);
  const int sb = tid >> 5;

  auto stage = [&](int hr) {
    __syncthreads();
    if ((unsigned)hr < (unsigned)HI) {
      const float* rowp = xb + ((size_t)lc * HI + hr) * WI;
      float4 a = *(const float4*)&rowp[lq * 4];
      float4 b = *(const float4*)&rowp[(lq + 8) * 4];
      raw[lc][lq * 4 + 0] = a.x; raw[lc][lq * 4 + 1] = a.y;
      raw[lc][lq * 4 + 2] = a.z; raw[lc][lq * 4 + 3] = a.w;
      raw[lc][(lq + 8) * 4 + 0] = b.x; raw[lc][(lq + 8) * 4 + 1] = b.y;
      raw[lc][(lq + 8) * 4 + 2] = b.z; raw[lc][(lq + 8) * 4 + 3] = b.w;
    }
    __syncthreads();
    const int slot = hr & 3;
    if ((unsigned)hr < (unsigned)HI) {
#pragma unroll
      for (int k = 0; k < 9; k++) {
        const int s = sb + (k << 3);
        if (s < HY) {
          float v = 0.f;
          if (s >= 2) v += raw[c][s - 2];
          if (s >= 1) v += 3.f * raw[c][s - 1];
          if (s <= 63) v += 3.f * raw[c][s];
          if (s <= 62) v += raw[c][s + 1];
          hrow[slot][s][c] = v;
        }
      }
    } else {
#pragma unroll
      for (int k = 0; k < 9; k++) {
        const int s = sb + (k << 3);
        if (s < HY) hrow[slot][s][c] = 0.f;
      }
    }
  };

  stage(r0 - 2);
  stage(r0 - 1);
  stage(r0);

  for (int i = 0; i < RT; i++) {
    const int r = r0 + i;
    stage(r + 1);
    __syncthreads();
    const int q0 = (r - 2) & 3, q1 = (r - 1) & 3, q2 = r & 3, q3 = (r + 1) & 3;
    unsigned short* yo = yt + (((size_t)n * HY + r) * HY) * CI + c0 + c;
#pragma unroll
    for (int k = 0; k < 9; k++) {
      const int s = sb + (k << 3);
      if (s < HY) {
        const float y = (hrow[q0][s][c] + 3.f * hrow[q1][s][c] +
                         3.f * hrow[q2][s][c] + hrow[q3][s][c]) * (1.f / 64.f);
        yo[(size_t)s * CI] = f2bf(y);
      }
    }
  }
}

// ---------------- Kernel B: weight transform ----------------
__global__ __launch_bounds__(256) void wt_kernel(const float* __restrict__ w,
                                                 unsigned short* __restrict__ wtb) {
  const int gid = blockIdx.x * 256 + threadIdx.x;
  const int ci = gid & (CI - 1);
  const int co = gid >> 9;
  const float* src = w + ((size_t)co * CI + ci) * 9;
#pragma unroll
  for (int t = 0; t < 9; t++) {
    wtb[((size_t)t * CO + co) * CI + ci] = f2bf(src[t]);
  }
}

// ---------------- Kernel C: implicit-GEMM conv ----------------
// Tile: 64 co x 128 pos, BK=64 ci, 72 k-steps (9 taps x 8 ci-blocks).
// 3-buffer LDS pipeline, depth-2 prefetch via global_load_lds, counted
// s_waitcnt vmcnt(6) + raw s_barrier (T3/T4). XOR slot swizzle both sides.
// Per iter: stage buf[(k+2)%3] (no concurrent reader: all waves between
// barriers read buf[k%3]); compute buf[k%3]; vmcnt(6)=stage(k+1) landed.
__global__ __launch_bounds__(256, 2) void conv_kernel(
    const unsigned short* __restrict__ wtb,
    const unsigned short* __restrict__ yt,
    const float* __restrict__ bias,
    float* __restrict__ out) {
  __shared__ unsigned short Alds[3][64 * 64];    // 3 x 8 KB
  __shared__ unsigned short Blds[3][128 * 64];   // 3 x 16 KB

  const int tid = threadIdx.x;
  const int wgid = ((blockIdx.x & 7) << 6) | (blockIdx.x >> 3);
  const int co_t = (wgid & 7) << 6;
  const int m0 = (wgid >> 3) << 7;
  const int n = m0 >> 10;
  const int w = tid >> 6, l = tid & 63;

  // ---- staging lane-invariant global offsets (swizzled source) ----
  size_t aoff[2];
#pragma unroll
  for (int i = 0; i < 2; i++) {
    const int cch = i * 256 + w * 64 + l;        // A chunk id 0..511
    const int row = cch >> 3, s = cch & 7;
    aoff[i] = (size_t)(co_t + row) * CI + ((s ^ (row & 7)) << 3);
  }
  size_t boff[4];
#pragma unroll
  for (int i = 0; i < 4; i++) {
    const int cch = i * 256 + w * 64 + l;        // B chunk id 0..1023
    const int p = cch >> 3, s = cch & 7;
    const int pos = m0 + p;
    const int ho = (pos & 1023) >> 5, wo = pos & 31;
    boff[i] = (((size_t)n * HY + 2 * ho) * HY + 2 * wo) * CI + ((s ^ (p & 7)) << 3);
  }

  auto stage = [&](int b, int ks) {
    const int tap = ks >> 3;
    const int ci0 = (ks & 7) << 6;
    const int kh = tap / 3, kw = tap - kh * 3;
    const size_t ka = (size_t)tap * (CO * CI) + ci0;
    const size_t kb = (size_t)(kh * HY + kw) * CI + ci0;
    unsigned short* Ab = &Alds[b][0];
    unsigned short* Bb = &Blds[b][0];
#pragma unroll
    for (int i = 0; i < 2; i++)
      async16(Ab + (size_t)(i * 256 + w * 64 + l) * 8, wtb + ka + aoff[i]);
#pragma unroll
    for (int i = 0; i < 4; i++)
      async16(Bb + (size_t)(i * 256 + w * 64 + l) * 8, yt + kb + boff[i]);
  };

  // ---- compute-side fragment addresses (swizzled read) ----
  const int wco = (w >> 1) << 5;   // 0 / 32
  const int wpos = (w & 1) << 6;   // 0 / 64
  const int ll = l & 15, kg = l >> 4;
  const int a7 = ll & 7;

  int aidx[2][2], bidx[4][2];
#pragma unroll
  for (int m = 0; m < 2; m++)
#pragma unroll
    for (int kk = 0; kk < 2; kk++)
      aidx[m][kk] = (wco + m * 16 + ll) * 64 + ((((kk << 2) | kg) ^ a7) << 3);
#pragma unroll
  for (int nf = 0; nf < 4; nf++)
#pragma unroll
    for (int kk = 0; kk < 2; kk++)
      bidx[nf][kk] = (wpos + nf * 16 + ll) * 64 + ((((kk << 2) | kg) ^ a7) << 3);

  f32x4 acc[2][4] = {};

  stage(0, 0);
  stage(1, 1);
  asm volatile("s_waitcnt vmcnt(6)" ::: "memory");   // stage(0) landed
  __builtin_amdgcn_s_barrier();

  int cur = 0;
  for (int ks = 0; ks < 72; ks++) {
    if (ks < 70) {
      int nb = cur + 2; if (nb >= 3) nb -= 3;
      stage(nb, ks + 2);                 // depth-2 prefetch, stays in flight
    }
    const unsigned short* Ac = &Alds[cur][0];
    const unsigned short* Bc = &Blds[cur][0];
#pragma unroll
    for (int kk = 0; kk < 2; kk++) {
      const bf16x8 a0 = *(const bf16x8*)(Ac + aidx[0][kk]);
      const bf16x8 a1 = *(const bf16x8*)(Ac + aidx[1][kk]);
      const bf16x8 b0 = *(const bf16x8*)(Bc + bidx[0][kk]);
      const bf16x8 b1 = *(const bf16x8*)(Bc + bidx[1][kk]);
      const bf16x8 b2 = *(const bf16x8*)(Bc + bidx[2][kk]);
      const bf16x8 b3 = *(const bf16x8*)(Bc + bidx[3][kk]);
      acc[0][0] = __builtin_amdgcn_mfma_f32_16x16x32_bf16(a0, b0, acc[0][0], 0, 0, 0);
      acc[0][1] = __builtin_amdgcn_mfma_f32_16x16x32_bf16(a0, b1, acc[0][1], 0, 0, 0);
      acc[0][2] = __builtin_amdgcn_mfma_f32_16x16x32_bf16(a0, b2, acc[0][2], 0, 0, 0);
      acc[0][3] = __builtin_amdgcn_mfma_f32_16x16x32_bf16(a0, b3, acc[0][3], 0, 0, 0);
      acc[1][0] = __builtin_amdgcn_mfma_f32_16x16x32_bf16(a1, b0, acc[1][0], 0, 0, 0);
      acc[1][1] = __builtin_amdgcn_mfma_f32_16x16x32_bf16(a1, b1, acc[1][1], 0, 0, 0);
      acc[1][2] = __builtin_amdgcn_mfma_f32_16x16x32_bf16(a1, b2, acc[1][2], 0, 0, 0);
      acc[1][3] = __builtin_amdgcn_mfma_f32_16x16x32_bf16(a1, b3, acc[1][3], 0, 0, 0);
    }
    if (ks < 70) {
      asm volatile("s_waitcnt vmcnt(6)" ::: "memory");  // stage(ks+1) landed
      __builtin_amdgcn_s_barrier();
    } else if (ks == 70) {
      asm volatile("s_waitcnt vmcnt(0)" ::: "memory");  // stage(71) landed
      __builtin_amdgcn_s_barrier();
    }
    if (++cur == 3) cur = 0;
  }

  // Epilogue: C/D row=(lane>>4)*4+reg -> co; col=lane&15 -> pos (verified layout)
#pragma unroll
  for (int i = 0; i < 2; i++) {
#pragma unroll
    for (int r = 0; r < 4; r++) {
      const int co = co_t + wco + i * 16 + kg * 4 + r;
      const float bv = bias[co];
#pragma unroll
      for (int j = 0; j < 4; j++) {
        const int pos = m0 + wpos + j * 16 + ll;
        const int ho = (pos & 1023) >> 5;
        const int wo = pos & 31;
        out[(((size_t)n * CO + co) * 32 + ho) * 32 + wo] = acc[i][j][r] + bv;
      }
    }
  }
}

extern "C" void kernel_launch(void* const* d_in, const int* in_sizes, int n_in,
                              void* d_out, int out_size, void* d_ws, size_t ws_size,
                              hipStream_t stream) {
  const float* x = (const float*)d_in[0];     // [8,512,64,64]
  const float* w = (const float*)d_in[1];     // [512,512,3,3]
  const float* bias = (const float*)d_in[2];  // [512]
  float* out = (float*)d_out;                 // [8,512,32,32]

  unsigned short* yt = (unsigned short*)d_ws;                    // 8*65*65*512 bf16
  unsigned short* wtb = yt + (size_t)NB * HY * HY * CI;          // 9*512*512 bf16

  fir_kernel<<<NB * (CI / CT) * 5, 256, 0, stream>>>(x, yt);     // 640 blocks
  wt_kernel<<<(CO * CI) / 256, 256, 0, stream>>>(w, wtb);        // 1024 blocks
  conv_kernel<<<512, 256, 0, stream>>>(wtb, yt, bias, out);      // 512 blocks
}